// Round 1
// baseline (501.909 us; speedup 1.0000x reference)
//
#include <hip/hip_runtime.h>
#include <hip/hip_bf16.h>
#include <float.h>
#include <math.h>

#define NB 32
#define NS 4096
#define NE 1024
#define ND 1024
#define NA 512

typedef __attribute__((ext_vector_type(4))) float f32x4;
typedef __attribute__((ext_vector_type(8))) short short8;

static __device__ __forceinline__ ushort f2bf(float f){
    union { float f; unsigned int u; } x; x.f = f;
    unsigned int u = x.u + 0x7fffu + ((x.u >> 16) & 1u);
    return (ushort)(u >> 16);
}

// ---- K1a: W_h (1024x512 f32) -> W_hT (512x1024 bf16) ----
__global__ __launch_bounds__(256) void k_prep_wht(const float* __restrict__ Wh,
                                                  ushort* __restrict__ WT){
    int i = blockIdx.x * 256 + threadIdx.x;   // 524288 elements
    int k = i >> 9, a = i & 511;
    WT[a * 1024 + k] = f2bf(Wh[i]);
}

// ---- K1b: proj_dec partials: pdp[kc][b][a] = sum_{k in chunk} dec[b][k]*Ws[k][a] ----
__global__ __launch_bounds__(512) void k_projdec(const float* __restrict__ dec,
                                                 const float* __restrict__ Ws,
                                                 float* __restrict__ pdp){
    int b = blockIdx.x >> 2, kc = blockIdx.x & 3;
    int a = threadIdx.x;
    const float* dp = dec + b * ND + kc * 256;
    const float* wp = Ws + (size_t)(kc * 256) * NA + a;
    float acc = 0.f;
    #pragma unroll 4
    for (int k = 0; k < 256; k++) acc += dp[k] * wp[(size_t)k * NA];
    pdp[(kc * NB + b) * NA + a] = acc;
}

// ---- K2: fused scores GEMM: scores[b][s] = v . tanh(E[b,s,:]@W_h + proj_dec[b,:]) ----
__global__ __launch_bounds__(512) void k_scores(const float* __restrict__ E,
                                                const ushort* __restrict__ WT,
                                                const float* __restrict__ pdp,
                                                const float* __restrict__ v,
                                                float* __restrict__ scores){
    const int t = threadIdx.x;
    const int wave = t >> 6, lane = t & 63;
    const int grp = lane >> 4, l15 = lane & 15;
    const int blk = blockIdx.x;
    const int b = blk >> 6;
    const int s0 = (blk & 63) << 6;

    __shared__ __align__(16) ushort lds[2][64 * 128];  // 2 x 16KB bf16 E-tiles
    __shared__ float sc[64][8];

    // staging: thread -> (row, 16-float segment)
    const int srow = t >> 3, sseg = t & 7;
    const float* gsrc = E + ((size_t)(b * NS + s0 + srow)) * NE + sseg * 16;
    const unsigned int wb = (unsigned int)(srow * 256 + sseg * 32);
    const unsigned int sw = (unsigned int)((srow & 7) << 4);

    f32x4 st[4];
    f32x4 acc[4][4];
    f32x4 zero; zero[0]=0.f; zero[1]=0.f; zero[2]=0.f; zero[3]=0.f;
    #pragma unroll
    for (int m = 0; m < 4; m++)
        #pragma unroll
        for (int n = 0; n < 4; n++) acc[m][n] = zero;

    auto load_step = [&](int step){
        const f32x4* p = (const f32x4*)(gsrc + step * 128);
        st[0] = p[0]; st[1] = p[1]; st[2] = p[2]; st[3] = p[3];
    };
    auto write_step = [&](int buf){
        ushort h[16];
        #pragma unroll
        for (int q = 0; q < 4; q++)
            #pragma unroll
            for (int e = 0; e < 4; e++) h[q * 4 + e] = f2bf(st[q][e]);
        short8 lo, hi;
        #pragma unroll
        for (int e = 0; e < 8; e++) { lo[e] = (short)h[e]; hi[e] = (short)h[8 + e]; }
        char* base = (char*)&lds[buf][0];
        *(short8*)(base + (wb ^ sw)) = lo;
        *(short8*)(base + ((wb + 16) ^ sw)) = hi;
    };
    auto compute_step = [&](int buf, int step){
        const char* base = (const char*)&lds[buf][0];
        const int kbase = step * 128;
        #pragma unroll
        for (int kk = 0; kk < 4; kk++){
            short8 af[4], bfr[4];
            #pragma unroll
            for (int m = 0; m < 4; m++){
                int row = m * 16 + l15;
                unsigned int off = (unsigned int)(row * 256 + kk * 64 + grp * 16);
                af[m] = *(const short8*)(base + (off ^ (unsigned int)((row & 7) << 4)));
            }
            #pragma unroll
            for (int n = 0; n < 4; n++){
                int c = wave * 64 + n * 16 + l15;
                bfr[n] = *(const short8*)(WT + (size_t)c * 1024 + kbase + kk * 32 + grp * 8);
            }
            #pragma unroll
            for (int m = 0; m < 4; m++)
                #pragma unroll
                for (int n = 0; n < 4; n++)
                    acc[m][n] = __builtin_amdgcn_mfma_f32_16x16x32_bf16(af[m], bfr[n], acc[m][n], 0, 0, 0);
        }
    };

    load_step(0); write_step(0); load_step(1);
    __syncthreads();
    for (int step = 0; step < 8; step++){
        int buf = step & 1;
        if (step < 7) write_step(buf ^ 1);
        if (step < 6) load_step(step + 2);
        compute_step(buf, step);
        __syncthreads();
    }

    // epilogue: tanh + v-dot + row reduce
    float pdc[4], vc[4];
    #pragma unroll
    for (int n = 0; n < 4; n++){
        int c = wave * 64 + n * 16 + l15;
        float p = 0.f;
        #pragma unroll
        for (int kc = 0; kc < 4; kc++) p += pdp[(kc * NB + b) * NA + c];
        pdc[n] = p;
        vc[n] = v[c];
    }
    #pragma unroll
    for (int m = 0; m < 4; m++){
        #pragma unroll
        for (int j = 0; j < 4; j++){
            float s = 0.f;
            #pragma unroll
            for (int n = 0; n < 4; n++) s += tanhf(acc[m][n][j] + pdc[n]) * vc[n];
            s += __shfl_xor(s, 1);
            s += __shfl_xor(s, 2);
            s += __shfl_xor(s, 4);
            s += __shfl_xor(s, 8);
            if (l15 == 0) sc[m * 16 + grp * 4 + j][wave] = s;
        }
    }
    __syncthreads();
    if (t < 64){
        float s = 0.f;
        #pragma unroll
        for (int w = 0; w < 8; w++) s += sc[t][w];
        scores[b * NS + s0 + t] = s;
    }
}

// ---- K3: masked softmax over S per batch row ----
__global__ __launch_bounds__(256) void k_softmax(const float* __restrict__ scores,
                                                 const int* __restrict__ mask,
                                                 float* __restrict__ weights){
    int b = blockIdx.x, t = threadIdx.x;
    __shared__ float red[8];
    float vals[16];
    float mx = -FLT_MAX;
    #pragma unroll
    for (int i = 0; i < 16; i++){
        int s = i * 256 + t;
        float x = scores[b * NS + s];
        x = (mask[b * NS + s] != 0) ? x : -FLT_MAX;
        vals[i] = x;
        mx = fmaxf(mx, x);
    }
    #pragma unroll
    for (int off = 32; off; off >>= 1) mx = fmaxf(mx, __shfl_xor(mx, off));
    int wv = t >> 6;
    if ((t & 63) == 0) red[wv] = mx;
    __syncthreads();
    mx = fmaxf(fmaxf(red[0], red[1]), fmaxf(red[2], red[3]));
    float sum = 0.f;
    #pragma unroll
    for (int i = 0; i < 16; i++){ vals[i] = __expf(vals[i] - mx); sum += vals[i]; }
    #pragma unroll
    for (int off = 32; off; off >>= 1) sum += __shfl_xor(sum, off);
    if ((t & 63) == 0) red[4 + wv] = sum;
    __syncthreads();
    sum = red[4] + red[5] + red[6] + red[7];
    float inv = 1.f / sum;
    #pragma unroll
    for (int i = 0; i < 16; i++) weights[b * NS + i * 256 + t] = vals[i] * inv;
}

// ---- K4: context partials over S-chunks ----
__global__ __launch_bounds__(256) void k_context(const float* __restrict__ E,
                                                 const float* __restrict__ weights,
                                                 float* __restrict__ part){
    int b = blockIdx.x >> 3, ch = blockIdx.x & 7;
    int t = threadIdx.x;
    __shared__ float wsm[512];
    wsm[t] = weights[b * NS + ch * 512 + t];
    wsm[256 + t] = weights[b * NS + ch * 512 + 256 + t];
    __syncthreads();
    const f32x4* Ep = (const f32x4*)(E + ((size_t)b * NS + ch * 512) * NE) + t;
    f32x4 acc; acc[0]=0.f; acc[1]=0.f; acc[2]=0.f; acc[3]=0.f;
    #pragma unroll 4
    for (int s = 0; s < 512; s++){
        f32x4 e = Ep[(size_t)s * 256];
        float w = wsm[s];
        acc[0] += w * e[0]; acc[1] += w * e[1];
        acc[2] += w * e[2]; acc[3] += w * e[3];
    }
    float* pp = part + ((size_t)(b * 8 + ch)) * NE + t * 4;
    pp[0] = acc[0]; pp[1] = acc[1]; pp[2] = acc[2]; pp[3] = acc[3];
}

// ---- K5: reduce context partials ----
__global__ __launch_bounds__(256) void k_reduce_ctx(const float* __restrict__ part,
                                                    float* __restrict__ ctx){
    int i = blockIdx.x * 256 + threadIdx.x;  // 32768
    int b = i >> 10, e = i & 1023;
    float s = 0.f;
    #pragma unroll
    for (int ch = 0; ch < 8; ch++) s += part[((size_t)(b * 8 + ch)) * NE + e];
    ctx[i] = s;
}

extern "C" void kernel_launch(void* const* d_in, const int* in_sizes, int n_in,
                              void* d_out, int out_size, void* d_ws, size_t ws_size,
                              hipStream_t stream){
    const float* dec  = (const float*)d_in[0];
    const float* E    = (const float*)d_in[1];
    const int*   mask = (const int*)d_in[2];
    const float* Wh   = (const float*)d_in[3];
    const float* Ws   = (const float*)d_in[4];
    const float* v    = (const float*)d_in[5];
    float* ctx = (float*)d_out;               // (32,1024)
    float* weights = (float*)d_out + NB * NE; // (32,4096)

    char* ws = (char*)d_ws;
    ushort* WT   = (ushort*)ws;                                     // 1 MB bf16 W_hT
    float*  pdp  = (float*)(ws + (1 << 20));                        // 256 KB proj_dec partials
    float*  scr  = (float*)(ws + (1 << 20) + (256 << 10));          // 512 KB scores
    float*  part = (float*)(ws + (1 << 20) + (256 << 10) + (512 << 10)); // 1 MB ctx partials

    k_prep_wht<<<2048, 256, 0, stream>>>(Wh, WT);
    k_projdec<<<128, 512, 0, stream>>>(dec, Ws, pdp);
    k_scores<<<2048, 512, 0, stream>>>(E, WT, pdp, v, scr);
    k_softmax<<<32, 256, 0, stream>>>(scr, mask, weights);
    k_context<<<256, 256, 0, stream>>>(E, weights, part);
    k_reduce_ctx<<<128, 256, 0, stream>>>(part, ctx);
}

// Round 2
// 449.232 us; speedup vs baseline: 1.1173x; 1.1173x over previous
//
#include <hip/hip_runtime.h>
#include <hip/hip_bf16.h>
#include <float.h>
#include <math.h>

#define NB 32
#define NS 4096
#define NE 1024
#define ND 1024
#define NA 512

typedef __attribute__((ext_vector_type(4))) float f32x4;
typedef __attribute__((ext_vector_type(8))) short short8;
typedef __attribute__((ext_vector_type(4))) short short4v;
typedef __attribute__((address_space(3))) char lds_char_t;
typedef __attribute__((address_space(1))) const char g_char_t;

static __device__ __forceinline__ ushort f2bf(float f){
    union { float f; unsigned int u; } x; x.f = f;
    unsigned int u = x.u + 0x7fffu + ((x.u >> 16) & 1u);
    return (ushort)(u >> 16);
}

// ---- K1a: W_h (1024x512 f32) -> W_hT (512x1024 bf16) ----
__global__ __launch_bounds__(256) void k_prep_wht(const float* __restrict__ Wh,
                                                  ushort* __restrict__ WT){
    int i = blockIdx.x * 256 + threadIdx.x;   // 524288 elements
    int k = i >> 9, a = i & 511;
    WT[a * 1024 + k] = f2bf(Wh[i]);
}

// ---- K1b: proj_dec partials ----
__global__ __launch_bounds__(512) void k_projdec(const float* __restrict__ dec,
                                                 const float* __restrict__ Ws,
                                                 float* __restrict__ pdp){
    int b = blockIdx.x >> 2, kc = blockIdx.x & 3;
    int a = threadIdx.x;
    const float* dp = dec + b * ND + kc * 256;
    const float* wp = Ws + (size_t)(kc * 256) * NA + a;
    float acc = 0.f;
    #pragma unroll 4
    for (int k = 0; k < 256; k++) acc += dp[k] * wp[(size_t)k * NA];
    pdp[(kc * NB + b) * NA + a] = acc;
}

// ---- K2: fused scores GEMM, DMA-staged, 2 blocks/CU target ----
__global__ __launch_bounds__(512, 4) void k_scores(const float* __restrict__ E,
                                                   const ushort* __restrict__ WT,
                                                   const float* __restrict__ pdp,
                                                   const float* __restrict__ v,
                                                   float* __restrict__ scores){
    const int t = threadIdx.x;
    const int wave = t >> 6, lane = t & 63;
    const int grp = lane >> 4, l15 = lane & 15;
    const int b = blockIdx.x >> 6;
    const int s0 = (blockIdx.x & 63) << 6;

    __shared__ __align__(16) float  f32t[2][64 * 64];   // 2 x 16KB f32 tiles (DMA dest)
    __shared__ __align__(16) ushort bft[64 * 64];       // 8KB bf16 tile (swizzled)
    __shared__ float sc[64][8];

    // DMA mapping: thread covers 16B chunks c0 = wave*128+lane, c1 = c0+64.
    // chunk c <-> (row c>>4, float-group c&15) of the 64x64 f32 tile.
    const int c0 = wave * 128 + lane;
    const int c1 = c0 + 64;
    const float* g0 = E + ((size_t)(b * NS + s0 + (c0 >> 4))) * NE + (c0 & 15) * 4;
    const float* g1 = E + ((size_t)(b * NS + s0 + (c1 >> 4))) * NE + (c1 & 15) * 4;

    f32x4 acc[4][4];
    f32x4 zero; zero[0]=0.f; zero[1]=0.f; zero[2]=0.f; zero[3]=0.f;
    #pragma unroll
    for (int m = 0; m < 4; m++)
        #pragma unroll
        for (int n = 0; n < 4; n++) acc[m][n] = zero;

    auto dma = [&](int buf, int it){
        char* l0 = (char*)&f32t[buf][0] + c0 * 16;
        char* l1 = (char*)&f32t[buf][0] + c1 * 16;
        __builtin_amdgcn_global_load_lds((g_char_t*)(g0 + it * 64), (lds_char_t*)l0, 16, 0, 0);
        __builtin_amdgcn_global_load_lds((g_char_t*)(g1 + it * 64), (lds_char_t*)l1, 16, 0, 0);
    };

    // convert: thread t handles chunks t (rows 0..31) and t+512 (rows 32..63)
    auto convert = [&](int buf){
        const f32x4* src = (const f32x4*)&f32t[buf][0];
        f32x4 alo = src[t];
        f32x4 ahi = src[t + 512];
        int rlo = t >> 4, rhi = 32 + rlo;
        unsigned colb = (unsigned)((t & 15) * 8);
        short4v hlo, hhi;
        #pragma unroll
        for (int e = 0; e < 4; e++){ hlo[e] = (short)f2bf(alo[e]); hhi[e] = (short)f2bf(ahi[e]); }
        unsigned blo = ((unsigned)(rlo * 128) + colb) ^ ((unsigned)(rlo & 7) << 4);
        unsigned bhi = ((unsigned)(rhi * 128) + colb) ^ ((unsigned)(rhi & 7) << 4);
        *(short4v*)((char*)bft + blo) = hlo;
        *(short4v*)((char*)bft + bhi) = hhi;
    };

    auto compute = [&](int it){
        #pragma unroll
        for (int kk = 0; kk < 2; kk++){
            short8 af[4], bfr[4];
            #pragma unroll
            for (int m = 0; m < 4; m++){
                int row = m * 16 + l15;
                unsigned off = (unsigned)(row * 128 + kk * 64 + grp * 16);
                af[m] = *(const short8*)((const char*)bft + (off ^ ((unsigned)(row & 7) << 4)));
            }
            #pragma unroll
            for (int n = 0; n < 4; n++){
                int c = wave * 64 + n * 16 + l15;
                bfr[n] = *(const short8*)(WT + (size_t)c * 1024 + it * 64 + kk * 32 + grp * 8);
            }
            #pragma unroll
            for (int m = 0; m < 4; m++)
                #pragma unroll
                for (int n = 0; n < 4; n++)
                    acc[m][n] = __builtin_amdgcn_mfma_f32_16x16x32_bf16(af[m], bfr[n], acc[m][n], 0, 0, 0);
        }
    };

    // prologue
    dma(0, 0);
    asm volatile("s_waitcnt vmcnt(0)" ::: "memory");
    __builtin_amdgcn_s_barrier();
    asm volatile("" ::: "memory");

    for (int it = 0; it < 16; it++){
        if (it < 15) dma((it + 1) & 1, it + 1);   // async next-tile DMA, in flight through phase
        convert(it & 1);                           // f32 LDS -> bf16 LDS (once per element)
        asm volatile("s_waitcnt lgkmcnt(0)" ::: "memory");
        __builtin_amdgcn_s_barrier();              // bf16 tile ready (DMA still in flight)
        asm volatile("" ::: "memory");
        compute(it);
        asm volatile("s_waitcnt vmcnt(0) lgkmcnt(0)" ::: "memory");
        __builtin_amdgcn_s_barrier();              // next f32 tile landed; bf16 reads drained
        asm volatile("" ::: "memory");
    }

    // epilogue: tanh + v-dot + row reduce
    float pdc[4], vc[4];
    #pragma unroll
    for (int n = 0; n < 4; n++){
        int c = wave * 64 + n * 16 + l15;
        float p = 0.f;
        #pragma unroll
        for (int kc = 0; kc < 4; kc++) p += pdp[(kc * NB + b) * NA + c];
        pdc[n] = p;
        vc[n] = v[c];
    }
    #pragma unroll
    for (int m = 0; m < 4; m++){
        #pragma unroll
        for (int j = 0; j < 4; j++){
            float s = 0.f;
            #pragma unroll
            for (int n = 0; n < 4; n++) s += tanhf(acc[m][n][j] + pdc[n]) * vc[n];
            s += __shfl_xor(s, 1);
            s += __shfl_xor(s, 2);
            s += __shfl_xor(s, 4);
            s += __shfl_xor(s, 8);
            if (l15 == 0) sc[m * 16 + grp * 4 + j][wave] = s;
        }
    }
    __syncthreads();
    if (t < 64){
        float s = 0.f;
        #pragma unroll
        for (int w = 0; w < 8; w++) s += sc[t][w];
        scores[b * NS + s0 + t] = s;
    }
}

// ---- K3: masked softmax over S per batch row ----
__global__ __launch_bounds__(256) void k_softmax(const float* __restrict__ scores,
                                                 const int* __restrict__ mask,
                                                 float* __restrict__ weights){
    int b = blockIdx.x, t = threadIdx.x;
    __shared__ float red[8];
    float vals[16];
    float mx = -FLT_MAX;
    #pragma unroll
    for (int i = 0; i < 16; i++){
        int s = i * 256 + t;
        float x = scores[b * NS + s];
        x = (mask[b * NS + s] != 0) ? x : -FLT_MAX;
        vals[i] = x;
        mx = fmaxf(mx, x);
    }
    #pragma unroll
    for (int off = 32; off; off >>= 1) mx = fmaxf(mx, __shfl_xor(mx, off));
    int wv = t >> 6;
    if ((t & 63) == 0) red[wv] = mx;
    __syncthreads();
    mx = fmaxf(fmaxf(red[0], red[1]), fmaxf(red[2], red[3]));
    float sum = 0.f;
    #pragma unroll
    for (int i = 0; i < 16; i++){ vals[i] = __expf(vals[i] - mx); sum += vals[i]; }
    #pragma unroll
    for (int off = 32; off; off >>= 1) sum += __shfl_xor(sum, off);
    if ((t & 63) == 0) red[4 + wv] = sum;
    __syncthreads();
    sum = red[4] + red[5] + red[6] + red[7];
    float inv = 1.f / sum;
    #pragma unroll
    for (int i = 0; i < 16; i++) weights[b * NS + i * 256 + t] = vals[i] * inv;
}

// ---- K4: context partials over S-chunks ----
__global__ __launch_bounds__(256) void k_context(const float* __restrict__ E,
                                                 const float* __restrict__ weights,
                                                 float* __restrict__ part){
    int b = blockIdx.x >> 3, ch = blockIdx.x & 7;
    int t = threadIdx.x;
    __shared__ float wsm[512];
    wsm[t] = weights[b * NS + ch * 512 + t];
    wsm[256 + t] = weights[b * NS + ch * 512 + 256 + t];
    __syncthreads();
    const f32x4* Ep = (const f32x4*)(E + ((size_t)b * NS + ch * 512) * NE) + t;
    f32x4 acc; acc[0]=0.f; acc[1]=0.f; acc[2]=0.f; acc[3]=0.f;
    #pragma unroll 4
    for (int s = 0; s < 512; s++){
        f32x4 e = Ep[(size_t)s * 256];
        float w = wsm[s];
        acc[0] += w * e[0]; acc[1] += w * e[1];
        acc[2] += w * e[2]; acc[3] += w * e[3];
    }
    float* pp = part + ((size_t)(b * 8 + ch)) * NE + t * 4;
    pp[0] = acc[0]; pp[1] = acc[1]; pp[2] = acc[2]; pp[3] = acc[3];
}

// ---- K5: reduce context partials ----
__global__ __launch_bounds__(256) void k_reduce_ctx(const float* __restrict__ part,
                                                    float* __restrict__ ctx){
    int i = blockIdx.x * 256 + threadIdx.x;  // 32768
    int b = i >> 10, e = i & 1023;
    float s = 0.f;
    #pragma unroll
    for (int ch = 0; ch < 8; ch++) s += part[((size_t)(b * 8 + ch)) * NE + e];
    ctx[i] = s;
}

extern "C" void kernel_launch(void* const* d_in, const int* in_sizes, int n_in,
                              void* d_out, int out_size, void* d_ws, size_t ws_size,
                              hipStream_t stream){
    const float* dec  = (const float*)d_in[0];
    const float* E    = (const float*)d_in[1];
    const int*   mask = (const int*)d_in[2];
    const float* Wh   = (const float*)d_in[3];
    const float* Ws   = (const float*)d_in[4];
    const float* v    = (const float*)d_in[5];
    float* ctx = (float*)d_out;               // (32,1024)
    float* weights = (float*)d_out + NB * NE; // (32,4096)

    char* ws = (char*)d_ws;
    ushort* WT   = (ushort*)ws;                                     // 1 MB bf16 W_hT
    float*  pdp  = (float*)(ws + (1 << 20));                        // 256 KB proj_dec partials
    float*  scr  = (float*)(ws + (1 << 20) + (256 << 10));          // 512 KB scores
    float*  part = (float*)(ws + (1 << 20) + (256 << 10) + (512 << 10)); // 1 MB ctx partials

    k_prep_wht<<<2048, 256, 0, stream>>>(Wh, WT);
    k_projdec<<<128, 512, 0, stream>>>(dec, Ws, pdp);
    k_scores<<<2048, 512, 0, stream>>>(E, WT, pdp, v, scr);
    k_softmax<<<32, 256, 0, stream>>>(scr, mask, weights);
    k_context<<<256, 256, 0, stream>>>(E, weights, part);
    k_reduce_ctx<<<128, 256, 0, stream>>>(part, ctx);
}

// Round 3
// 432.451 us; speedup vs baseline: 1.1606x; 1.0388x over previous
//
#include <hip/hip_runtime.h>
#include <hip/hip_bf16.h>
#include <float.h>
#include <math.h>

#define NB 32
#define NS 4096
#define NE 1024
#define ND 1024
#define NA 512

typedef __attribute__((ext_vector_type(4))) float f32x4;
typedef __attribute__((ext_vector_type(8))) short short8;
typedef __attribute__((address_space(3))) char lds_char_t;
typedef __attribute__((address_space(1))) const char g_char_t;

static __device__ __forceinline__ ushort f2bf(float f){
    union { float f; unsigned int u; } x; x.f = f;
    unsigned int u = x.u + 0x7fffu + ((x.u >> 16) & 1u);
    return (ushort)(u >> 16);
}

// ---- K1a: W_h (1024x512 f32) -> W_hT (512x1024 bf16) ----
__global__ __launch_bounds__(256) void k_prep_wht(const float* __restrict__ Wh,
                                                  ushort* __restrict__ WT){
    int i = blockIdx.x * 256 + threadIdx.x;   // 524288 elements
    int k = i >> 9, a = i & 511;
    WT[a * 1024 + k] = f2bf(Wh[i]);
}

// ---- K1b: proj_dec partials ----
__global__ __launch_bounds__(512) void k_projdec(const float* __restrict__ dec,
                                                 const float* __restrict__ Ws,
                                                 float* __restrict__ pdp){
    int b = blockIdx.x >> 2, kc = blockIdx.x & 3;
    int a = threadIdx.x;
    const float* dp = dec + b * ND + kc * 256;
    const float* wp = Ws + (size_t)(kc * 256) * NA + a;
    float acc = 0.f;
    #pragma unroll 4
    for (int k = 0; k < 256; k++) acc += dp[k] * wp[(size_t)k * NA];
    pdp[(kc * NB + b) * NA + a] = acc;
}

// ---- K2: fused scores GEMM ----
// Per iter: syncthreads (drains only dma(it)) -> WT reg loads -> dma(it+1) -> compute.
// WT loads are OLDER than the in-flight DMA => compiler waits vmcnt(2), DMA never drained mid-phase.
__global__ __launch_bounds__(512, 4) void k_scores(const float* __restrict__ E,
                                                   const ushort* __restrict__ WT,
                                                   const float* __restrict__ pdp,
                                                   const float* __restrict__ v,
                                                   float* __restrict__ scores){
    const int t = threadIdx.x;
    const int wave = t >> 6, lane = t & 63;
    const int grp = lane >> 4, l15 = lane & 15;
    const int b = blockIdx.x >> 6;
    const int s0 = (blockIdx.x & 63) << 6;

    __shared__ __align__(16) float f32t[2][64 * 64];   // 2 x 16KB f32 E-tiles (DMA dest)
    __shared__ float sc[64][8];

    // DMA source mapping with XOR-swizzled segment position (seg ^ (row&7)):
    // LDS stays linear (chunk c at byte c*16); global source is permuted so that
    // logical (row r, seg s) lands at chunk r*16 + (s ^ (r&7)).
    const int c0 = wave * 128 + lane;
    const int c1 = c0 + 64;
    const int r0 = c0 >> 4, r1 = c1 >> 4;
    const int sd0 = (c0 & 15) ^ (r0 & 7);
    const int sd1 = (c1 & 15) ^ (r1 & 7);
    const float* g0 = E + ((size_t)(b * NS + s0 + r0)) * NE + sd0 * 4;
    const float* g1 = E + ((size_t)(b * NS + s0 + r1)) * NE + sd1 * 4;

    f32x4 acc[4][4];
    f32x4 zero; zero[0]=0.f; zero[1]=0.f; zero[2]=0.f; zero[3]=0.f;
    #pragma unroll
    for (int m = 0; m < 4; m++)
        #pragma unroll
        for (int n = 0; n < 4; n++) acc[m][n] = zero;

    auto dma = [&](int buf, int it){
        char* l0 = (char*)&f32t[buf][0] + c0 * 16;
        char* l1 = (char*)&f32t[buf][0] + c1 * 16;
        __builtin_amdgcn_global_load_lds((g_char_t*)(g0 + it * 64), (lds_char_t*)l0, 16, 0, 0);
        __builtin_amdgcn_global_load_lds((g_char_t*)(g1 + it * 64), (lds_char_t*)l1, 16, 0, 0);
    };

    dma(0, 0);

    const int cb = wave * 64 + l15;   // base output column for this lane

    for (int it = 0; it < 16; ++it){
        __syncthreads();   // drains dma(it) only; tile[it] visible to all; prev-buf reads done

        // 1) WT fragment loads (L2-hot), issued BEFORE the next DMA
        short8 wt[2][4];
        const ushort* wbase = WT + it * 64 + grp * 8;
        #pragma unroll
        for (int kk = 0; kk < 2; kk++)
            #pragma unroll
            for (int n = 0; n < 4; n++)
                wt[kk][n] = *(const short8*)(wbase + (size_t)(cb + n * 16) * 1024 + kk * 32);
        __builtin_amdgcn_sched_barrier(0);

        // 2) next-tile DMA (stays in flight through compute, drained at next syncthreads)
        if (it < 15) dma((it + 1) & 1, it + 1);
        __builtin_amdgcn_sched_barrier(0);

        // 3) compute from f32t[it&1]: ds_read f32 frags, convert in-reg, MFMA
        const char* base = (const char*)&f32t[it & 1][0];
        #pragma unroll
        for (int kk = 0; kk < 2; kk++){
            #pragma unroll
            for (int m = 0; m < 4; m++){
                const int r = m * 16 + l15;
                const int scg = kk * 8 + grp * 2;
                f32x4 lo = *(const f32x4*)(base + r * 256 + ((scg       ^ (r & 7)) << 4));
                f32x4 hi = *(const f32x4*)(base + r * 256 + (((scg + 1) ^ (r & 7)) << 4));
                short8 af;
                #pragma unroll
                for (int e = 0; e < 4; e++){
                    af[e]     = (short)__builtin_bit_cast(ushort, __float2bfloat16(lo[e]));
                    af[e + 4] = (short)__builtin_bit_cast(ushort, __float2bfloat16(hi[e]));
                }
                #pragma unroll
                for (int n = 0; n < 4; n++)
                    acc[m][n] = __builtin_amdgcn_mfma_f32_16x16x32_bf16(af, wt[kk][n], acc[m][n], 0, 0, 0);
            }
        }
    }

    // epilogue: tanh + v-dot + row reduce
    float pdc[4], vc[4];
    #pragma unroll
    for (int n = 0; n < 4; n++){
        int c = wave * 64 + n * 16 + l15;
        float p = 0.f;
        #pragma unroll
        for (int kc = 0; kc < 4; kc++) p += pdp[(kc * NB + b) * NA + c];
        pdc[n] = p;
        vc[n] = v[c];
    }
    #pragma unroll
    for (int m = 0; m < 4; m++){
        #pragma unroll
        for (int j = 0; j < 4; j++){
            float s = 0.f;
            #pragma unroll
            for (int n = 0; n < 4; n++) s += tanhf(acc[m][n][j] + pdc[n]) * vc[n];
            s += __shfl_xor(s, 1);
            s += __shfl_xor(s, 2);
            s += __shfl_xor(s, 4);
            s += __shfl_xor(s, 8);
            if (l15 == 0) sc[m * 16 + grp * 4 + j][wave] = s;
        }
    }
    __syncthreads();
    if (t < 64){
        float s = 0.f;
        #pragma unroll
        for (int w = 0; w < 8; w++) s += sc[t][w];
        scores[b * NS + s0 + t] = s;
    }
}

// ---- K3: masked softmax over S per batch row ----
__global__ __launch_bounds__(256) void k_softmax(const float* __restrict__ scores,
                                                 const int* __restrict__ mask,
                                                 float* __restrict__ weights){
    int b = blockIdx.x, t = threadIdx.x;
    __shared__ float red[8];
    float vals[16];
    float mx = -FLT_MAX;
    #pragma unroll
    for (int i = 0; i < 16; i++){
        int s = i * 256 + t;
        float x = scores[b * NS + s];
        x = (mask[b * NS + s] != 0) ? x : -FLT_MAX;
        vals[i] = x;
        mx = fmaxf(mx, x);
    }
    #pragma unroll
    for (int off = 32; off; off >>= 1) mx = fmaxf(mx, __shfl_xor(mx, off));
    int wv = t >> 6;
    if ((t & 63) == 0) red[wv] = mx;
    __syncthreads();
    mx = fmaxf(fmaxf(red[0], red[1]), fmaxf(red[2], red[3]));
    float sum = 0.f;
    #pragma unroll
    for (int i = 0; i < 16; i++){ vals[i] = __expf(vals[i] - mx); sum += vals[i]; }
    #pragma unroll
    for (int off = 32; off; off >>= 1) sum += __shfl_xor(sum, off);
    if ((t & 63) == 0) red[4 + wv] = sum;
    __syncthreads();
    sum = red[4] + red[5] + red[6] + red[7];
    float inv = 1.f / sum;
    #pragma unroll
    for (int i = 0; i < 16; i++) weights[b * NS + i * 256 + t] = vals[i] * inv;
}

// ---- K4: context partials over S-chunks (1024 thr: 4 row-quarters + LDS reduce) ----
__global__ __launch_bounds__(1024) void k_context(const float* __restrict__ E,
                                                  const float* __restrict__ weights,
                                                  float* __restrict__ part){
    int b = blockIdx.x >> 3, ch = blockIdx.x & 7;
    int t = threadIdx.x;
    int h = t >> 8, tg = t & 255;
    __shared__ float wsm[512];
    __shared__ __align__(16) f32x4 red[4][256];
    if (t < 512) wsm[t] = weights[b * NS + ch * 512 + t];
    __syncthreads();
    const f32x4* Ep = (const f32x4*)(E + ((size_t)b * NS + ch * 512 + h * 128) * NE) + tg;
    f32x4 acc; acc[0]=0.f; acc[1]=0.f; acc[2]=0.f; acc[3]=0.f;
    #pragma unroll 4
    for (int s = 0; s < 128; s++){
        f32x4 e = Ep[(size_t)s * 256];
        float w = wsm[h * 128 + s];
        acc[0] += w * e[0]; acc[1] += w * e[1];
        acc[2] += w * e[2]; acc[3] += w * e[3];
    }
    red[h][tg] = acc;
    __syncthreads();
    if (h == 0){
        f32x4 a0 = red[0][tg], a1 = red[1][tg], a2 = red[2][tg], a3 = red[3][tg];
        f32x4 s;
        s[0] = a0[0]+a1[0]+a2[0]+a3[0];
        s[1] = a0[1]+a1[1]+a2[1]+a3[1];
        s[2] = a0[2]+a1[2]+a2[2]+a3[2];
        s[3] = a0[3]+a1[3]+a2[3]+a3[3];
        *(f32x4*)(part + ((size_t)(b * 8 + ch)) * NE + tg * 4) = s;
    }
}

// ---- K5: reduce context partials ----
__global__ __launch_bounds__(256) void k_reduce_ctx(const float* __restrict__ part,
                                                    float* __restrict__ ctx){
    int i = blockIdx.x * 256 + threadIdx.x;  // 32768
    int b = i >> 10, e = i & 1023;
    float s = 0.f;
    #pragma unroll
    for (int ch = 0; ch < 8; ch++) s += part[((size_t)(b * 8 + ch)) * NE + e];
    ctx[i] = s;
}

extern "C" void kernel_launch(void* const* d_in, const int* in_sizes, int n_in,
                              void* d_out, int out_size, void* d_ws, size_t ws_size,
                              hipStream_t stream){
    const float* dec  = (const float*)d_in[0];
    const float* E    = (const float*)d_in[1];
    const int*   mask = (const int*)d_in[2];
    const float* Wh   = (const float*)d_in[3];
    const float* Ws   = (const float*)d_in[4];
    const float* v    = (const float*)d_in[5];
    float* ctx = (float*)d_out;               // (32,1024)
    float* weights = (float*)d_out + NB * NE; // (32,4096)

    char* ws = (char*)d_ws;
    // part (k_context, 1MB) overlaps WT (dead by then). Total ws use: 2.75MB.
    ushort* WT   = (ushort*)ws;                                     // 1 MB bf16 W_hT
    float*  part = (float*)ws;                                      // 1 MB ctx partials (after k_scores)
    float*  pdp  = (float*)(ws + (1 << 20));                        // 256 KB proj_dec partials
    float*  scr  = (float*)(ws + (1 << 20) + (256 << 10));          // 512 KB scores
    // 2MB..2.75MB free

    k_prep_wht<<<2048, 256, 0, stream>>>(Wh, WT);
    k_projdec<<<128, 512, 0, stream>>>(dec, Ws, pdp);
    k_scores<<<2048, 512, 0, stream>>>(E, WT, pdp, v, scr);
    k_softmax<<<32, 256, 0, stream>>>(scr, mask, weights);
    k_context<<<256, 1024, 0, stream>>>(E, weights, part);
    k_reduce_ctx<<<128, 256, 0, stream>>>(part, ctx);
}

// Round 4
// 413.306 us; speedup vs baseline: 1.2144x; 1.0463x over previous
//
#include <hip/hip_runtime.h>
#include <hip/hip_bf16.h>
#include <float.h>
#include <math.h>

#define NB 32
#define NS 4096
#define NE 1024
#define ND 1024
#define NA 512

typedef __attribute__((ext_vector_type(4))) float f32x4;
typedef __attribute__((ext_vector_type(8))) short short8;
typedef __attribute__((ext_vector_type(4))) short short4v;

static __device__ __forceinline__ ushort f2bf(float f){
    union { float f; unsigned int u; } x; x.f = f;
    unsigned int u = x.u + 0x7fffu + ((x.u >> 16) & 1u);
    return (ushort)(u >> 16);
}

// ---- K1a: W_h (1024x512 f32) -> W_hT (512x1024 bf16) ----
__global__ __launch_bounds__(256) void k_prep_wht(const float* __restrict__ Wh,
                                                  ushort* __restrict__ WT){
    int i = blockIdx.x * 256 + threadIdx.x;   // 524288 elements
    int k = i >> 9, a = i & 511;
    WT[a * 1024 + k] = f2bf(Wh[i]);
}

// ---- K1b: proj_dec partials ----
__global__ __launch_bounds__(512) void k_projdec(const float* __restrict__ dec,
                                                 const float* __restrict__ Ws,
                                                 float* __restrict__ pdp){
    int b = blockIdx.x >> 2, kc = blockIdx.x & 3;
    int a = threadIdx.x;
    const float* dp = dec + b * ND + kc * 256;
    const float* wp = Ws + (size_t)(kc * 256) * NA + a;
    float acc = 0.f;
    #pragma unroll 4
    for (int k = 0; k < 256; k++) acc += dp[k] * wp[(size_t)k * NA];
    pdp[(kc * NB + b) * NA + a] = acc;
}

// ---- K2: fused scores GEMM, bf16 LDS tile via reg-staging (T14 split) ----
// Per iter: barrier -> wt L2 loads -> stage_load(it+1) [newer => MFMA waits vmcnt(2)]
//           -> compute (bf16 ds_read + MFMA) -> vmcnt(0)+cvt+ds_write(it+1) -> barrier.
__global__ __launch_bounds__(512, 4) void k_scores(const float* __restrict__ E,
                                                   const ushort* __restrict__ WT,
                                                   const float* __restrict__ pdp,
                                                   const float* __restrict__ v,
                                                   float* __restrict__ scores){
    const int t = threadIdx.x;
    const int wave = t >> 6, lane = t & 63;
    const int grp = lane >> 4, l15 = lane & 15;
    const int b = blockIdx.x >> 6;
    const int s0 = (blockIdx.x & 63) << 6;

    __shared__ __align__(16) ushort bft[2][64 * 64];   // 2 x 8KB bf16 E-tiles (swizzled)
    __shared__ float sc[64][8];

    // staging map: thread t -> row r = t>>3, k-group c = t&7 (8 floats = 32B)
    const int sr = t >> 3, scg = t & 7;
    const float* gsrc = E + ((size_t)(b * NS + s0 + sr)) * NE + scg * 8;
    const unsigned swb = (unsigned)(sr * 128 + ((scg ^ (sr & 7)) << 4));  // LDS byte addr (swizzled)

    f32x4 stlo, sthi;   // staged 8 floats

    f32x4 acc[4][4];
    f32x4 zero; zero[0]=0.f; zero[1]=0.f; zero[2]=0.f; zero[3]=0.f;
    #pragma unroll
    for (int m = 0; m < 4; m++)
        #pragma unroll
        for (int n = 0; n < 4; n++) acc[m][n] = zero;

    auto stage_load = [&](int it){
        const f32x4* p = (const f32x4*)(gsrc + it * 64);
        stlo = p[0]; sthi = p[1];
    };
    auto stage_write = [&](int buf){
        short8 h;
        #pragma unroll
        for (int e = 0; e < 4; e++){
            h[e]     = (short)f2bf(stlo[e]);
            h[e + 4] = (short)f2bf(sthi[e]);
        }
        *(short8*)((char*)&bft[buf][0] + swb) = h;
    };

    const int cb = wave * 64 + l15;   // base output column for this lane

    stage_load(0);
    asm volatile("s_waitcnt vmcnt(0)" ::: "memory");
    stage_write(0);
    __builtin_amdgcn_s_barrier();

    for (int it = 0; it < 16; ++it){
        // 1) WT fragment loads (L2-hot), oldest in the vmem queue this iter
        short8 wt[2][4];
        const ushort* wbase = WT + it * 64 + grp * 8;
        #pragma unroll
        for (int kk = 0; kk < 2; kk++)
            #pragma unroll
            for (int n = 0; n < 4; n++)
                wt[kk][n] = *(const short8*)(wbase + (size_t)(cb + n * 16) * 1024 + kk * 32);
        __builtin_amdgcn_sched_barrier(0);

        // 2) next-tile global loads (newer; stay in flight through compute)
        if (it < 15) stage_load(it + 1);
        __builtin_amdgcn_sched_barrier(0);

        // 3) compute from bf16 LDS tile
        const char* base = (const char*)&bft[it & 1][0];
        #pragma unroll
        for (int kk = 0; kk < 2; kk++){
            #pragma unroll
            for (int m = 0; m < 4; m++){
                const int r = m * 16 + l15;
                const int g = kk * 4 + grp;
                short8 af = *(const short8*)(base + r * 128 + (((g ^ (r & 7)) << 4)));
                #pragma unroll
                for (int n = 0; n < 4; n++)
                    acc[m][n] = __builtin_amdgcn_mfma_f32_16x16x32_bf16(af, wt[kk][n], acc[m][n], 0, 0, 0);
            }
        }
        __builtin_amdgcn_sched_barrier(0);

        // 4) convert + LDS write for next tile, then one barrier
        if (it < 15){
            asm volatile("s_waitcnt vmcnt(0)" ::: "memory");
            stage_write((it + 1) & 1);
        }
        __builtin_amdgcn_s_barrier();
    }

    // epilogue: tanh + v-dot + row reduce
    float pdc[4], vc[4];
    #pragma unroll
    for (int n = 0; n < 4; n++){
        int c = wave * 64 + n * 16 + l15;
        float p = 0.f;
        #pragma unroll
        for (int kc = 0; kc < 4; kc++) p += pdp[(kc * NB + b) * NA + c];
        pdc[n] = p;
        vc[n] = v[c];
    }
    #pragma unroll
    for (int m = 0; m < 4; m++){
        #pragma unroll
        for (int j = 0; j < 4; j++){
            float s = 0.f;
            #pragma unroll
            for (int n = 0; n < 4; n++) s += tanhf(acc[m][n][j] + pdc[n]) * vc[n];
            s += __shfl_xor(s, 1);
            s += __shfl_xor(s, 2);
            s += __shfl_xor(s, 4);
            s += __shfl_xor(s, 8);
            if (l15 == 0) sc[m * 16 + grp * 4 + j][wave] = s;
        }
    }
    __syncthreads();
    if (t < 64){
        float s = 0.f;
        #pragma unroll
        for (int w = 0; w < 8; w++) s += sc[t][w];
        scores[b * NS + s0 + t] = s;
    }
}

// ---- K3: masked softmax over S per batch row ----
__global__ __launch_bounds__(256) void k_softmax(const float* __restrict__ scores,
                                                 const int* __restrict__ mask,
                                                 float* __restrict__ weights){
    int b = blockIdx.x, t = threadIdx.x;
    __shared__ float red[8];
    float vals[16];
    float mx = -FLT_MAX;
    #pragma unroll
    for (int i = 0; i < 16; i++){
        int s = i * 256 + t;
        float x = scores[b * NS + s];
        x = (mask[b * NS + s] != 0) ? x : -FLT_MAX;
        vals[i] = x;
        mx = fmaxf(mx, x);
    }
    #pragma unroll
    for (int off = 32; off; off >>= 1) mx = fmaxf(mx, __shfl_xor(mx, off));
    int wv = t >> 6;
    if ((t & 63) == 0) red[wv] = mx;
    __syncthreads();
    mx = fmaxf(fmaxf(red[0], red[1]), fmaxf(red[2], red[3]));
    float sum = 0.f;
    #pragma unroll
    for (int i = 0; i < 16; i++){ vals[i] = __expf(vals[i] - mx); sum += vals[i]; }
    #pragma unroll
    for (int off = 32; off; off >>= 1) sum += __shfl_xor(sum, off);
    if ((t & 63) == 0) red[4 + wv] = sum;
    __syncthreads();
    sum = red[4] + red[5] + red[6] + red[7];
    float inv = 1.f / sum;
    #pragma unroll
    for (int i = 0; i < 16; i++) weights[b * NS + i * 256 + t] = vals[i] * inv;
}

// ---- K4: context partials over S-chunks (1024 thr: 4 row-quarters + LDS reduce) ----
__global__ __launch_bounds__(1024) void k_context(const float* __restrict__ E,
                                                  const float* __restrict__ weights,
                                                  float* __restrict__ part){
    int b = blockIdx.x >> 3, ch = blockIdx.x & 7;
    int t = threadIdx.x;
    int h = t >> 8, tg = t & 255;
    __shared__ float wsm[512];
    __shared__ __align__(16) f32x4 red[4][256];
    if (t < 512) wsm[t] = weights[b * NS + ch * 512 + t];
    __syncthreads();
    const f32x4* Ep = (const f32x4*)(E + ((size_t)b * NS + ch * 512 + h * 128) * NE) + tg;
    f32x4 acc; acc[0]=0.f; acc[1]=0.f; acc[2]=0.f; acc[3]=0.f;
    #pragma unroll 4
    for (int s = 0; s < 128; s++){
        f32x4 e = Ep[(size_t)s * 256];
        float w = wsm[h * 128 + s];
        acc[0] += w * e[0]; acc[1] += w * e[1];
        acc[2] += w * e[2]; acc[3] += w * e[3];
    }
    red[h][tg] = acc;
    __syncthreads();
    if (h == 0){
        f32x4 a0 = red[0][tg], a1 = red[1][tg], a2 = red[2][tg], a3 = red[3][tg];
        f32x4 s;
        s[0] = a0[0]+a1[0]+a2[0]+a3[0];
        s[1] = a0[1]+a1[1]+a2[1]+a3[1];
        s[2] = a0[2]+a1[2]+a2[2]+a3[2];
        s[3] = a0[3]+a1[3]+a2[3]+a3[3];
        *(f32x4*)(part + ((size_t)(b * 8 + ch)) * NE + tg * 4) = s;
    }
}

// ---- K5: reduce context partials ----
__global__ __launch_bounds__(256) void k_reduce_ctx(const float* __restrict__ part,
                                                    float* __restrict__ ctx){
    int i = blockIdx.x * 256 + threadIdx.x;  // 32768
    int b = i >> 10, e = i & 1023;
    float s = 0.f;
    #pragma unroll
    for (int ch = 0; ch < 8; ch++) s += part[((size_t)(b * 8 + ch)) * NE + e];
    ctx[i] = s;
}

extern "C" void kernel_launch(void* const* d_in, const int* in_sizes, int n_in,
                              void* d_out, int out_size, void* d_ws, size_t ws_size,
                              hipStream_t stream){
    const float* dec  = (const float*)d_in[0];
    const float* E    = (const float*)d_in[1];
    const int*   mask = (const int*)d_in[2];
    const float* Wh   = (const float*)d_in[3];
    const float* Ws   = (const float*)d_in[4];
    const float* v    = (const float*)d_in[5];
    float* ctx = (float*)d_out;               // (32,1024)
    float* weights = (float*)d_out + NB * NE; // (32,4096)

    char* ws = (char*)d_ws;
    // part (k_context, 1MB) overlaps WT (dead by then). Total ws use: 2.75MB.
    ushort* WT   = (ushort*)ws;                                     // 1 MB bf16 W_hT
    float*  part = (float*)ws;                                      // 1 MB ctx partials (after k_scores)
    float*  pdp  = (float*)(ws + (1 << 20));                        // 256 KB proj_dec partials
    float*  scr  = (float*)(ws + (1 << 20) + (256 << 10));          // 512 KB scores
    // 2MB..2.75MB free

    k_prep_wht<<<2048, 256, 0, stream>>>(Wh, WT);
    k_projdec<<<128, 512, 0, stream>>>(dec, Ws, pdp);
    k_scores<<<2048, 512, 0, stream>>>(E, WT, pdp, v, scr);
    k_softmax<<<32, 256, 0, stream>>>(scr, mask, weights);
    k_context<<<256, 1024, 0, stream>>>(E, weights, part);
    k_reduce_ctx<<<128, 256, 0, stream>>>(part, ctx);
}